// Round 13
// baseline (162.522 us; speedup 1.0000x reference)
//
#include <hip/hip_runtime.h>

#define NCH 128
#define MAXBKT 512          // supports nN <= 65536 at 128 nodes/bucket
#define BKT_SHIFT 7         // 128 nodes per bucket
#define BKT_NODES 128
#define BIN_BATCH 4096      // edges per k_bin block (16/thread) — R8-proven
#define NHIST 512           // histogram blocks (2/CU; R12's 128 was 0.5/CU)

typedef __attribute__((ext_vector_type(8))) short bf16x8;
typedef __attribute__((ext_vector_type(4))) float f32x4;

__device__ __forceinline__ unsigned short f2bf_rne(float f) {
  unsigned u = __float_as_uint(f);
  unsigned r = u + 0x7FFF + ((u >> 16) & 1);
  return (unsigned short)(r >> 16);
}

// ---- prep helper: fragment-ordered SINGLE bf16 weights (RNE) ----------------
// Wf index = ((kc*8 + nt)*64 + lane)*8 + e; j = nt*16+(lane&15),
// k = kc*32+(lane>>4)*8+e. Single-bf16 W proven R12 (absmax stayed at floor).
__device__ __forceinline__ void prepW_elem(const float* __restrict__ Wl,
                                           const float* __restrict__ Wr,
                                           unsigned short* __restrict__ WF, int i) {
  int kc   = i >> 12;
  int r    = i & 4095;
  int nt   = r >> 9;
  int r2   = r & 511;
  int lane = r2 >> 3;
  int e    = r2 & 7;
  int j = nt * 16 + (lane & 15);
  int k = kc * 32 + (lane >> 4) * 8 + e;
  float w = (k < 128) ? Wl[j * 128 + k] : Wr[j * 128 + (k - 128)];
  WF[i] = f2bf_rne(w);
}

// ---- merged: bucket histogram (blocks < NHIST) + x->bf16 / W prep (rest) ----
// Hist: per-block LDS bins -> block-major partial[b*MAXBKT+slot] (contiguous
// 2KB writes; NO global atomics, NO init). Hist work hides under prep's
// 3381-block stream; saves one dispatch gap vs separate k_bkthist.
__global__ __launch_bounds__(256) void k_prep_hist(
    const int* __restrict__ dst, int* __restrict__ partial,
    const float* __restrict__ x, unsigned short* __restrict__ xbf,
    const float* __restrict__ W1l, const float* __restrict__ W1r,
    const float* __restrict__ W2l, const float* __restrict__ W2r,
    unsigned short* __restrict__ W1f, unsigned short* __restrict__ W2f,
    int nE, int n8) {
  int t = threadIdx.x;
  if (blockIdx.x < NHIST) {
    __shared__ int h[MAXBKT];
    h[t] = 0; h[t + 256] = 0;
    __syncthreads();
    for (int e = blockIdx.x * 256 + t; e < nE; e += NHIST * 256)
      atomicAdd(&h[dst[e] >> BKT_SHIFT], 1);
    __syncthreads();
    partial[blockIdx.x * MAXBKT + t] = h[t];
    partial[blockIdx.x * MAXBKT + t + 256] = h[t + 256];
  } else {
    int i = (blockIdx.x - NHIST) * 256 + t;
    if (i < n8) {                     // n8 = nN*NCH/8, multiple of 256
      const float4* p = reinterpret_cast<const float4*>(x + (size_t)i * 8);
      float4 v0 = p[0], v1 = p[1];
      uint4 o;
      o.x = (unsigned)f2bf_rne(v0.x) | ((unsigned)f2bf_rne(v0.y) << 16);
      o.y = (unsigned)f2bf_rne(v0.z) | ((unsigned)f2bf_rne(v0.w) << 16);
      o.z = (unsigned)f2bf_rne(v1.x) | ((unsigned)f2bf_rne(v1.y) << 16);
      o.w = (unsigned)f2bf_rne(v1.z) | ((unsigned)f2bf_rne(v1.w) << 16);
      *reinterpret_cast<uint4*>(xbf + (size_t)i * 8) = o;
    } else {
      int j = i - n8;
      if (j < 32768)       prepW_elem(W1l, W1r, W1f, j);
      else if (j < 65536)  prepW_elem(W2l, W2r, W2f, j - 32768);
    }
  }
}

// ---- sum partials + scan -> bktBase; zero bktCursor (replaces memset) -------
// Reads are wave-coalesced per iteration (thread t reads partial[b*512+t]).
__global__ __launch_bounds__(512) void k_bktscan(const int* __restrict__ partial,
                                                 int* __restrict__ bktBase,
                                                 int* __restrict__ bktCursor, int nBkt) {
  __shared__ int sc[512];
  int t = threadIdx.x;
  int v = 0;
#pragma unroll 16
  for (int b = 0; b < NHIST; b++) v += partial[b * MAXBKT + t];
  sc[t] = v;
  __syncthreads();
  for (int off = 1; off < 512; off <<= 1) {
    int u = (t >= off) ? sc[t - off] : 0;
    __syncthreads();
    sc[t] += u;
    __syncthreads();
  }
  bktBase[t] = sc[t] - v;            // buckets >= nBkt have v=0; harmless
  if (t == 511) bktBase[512] = sc[511];
  bktCursor[t] = 0;
}

// ---- bin edges into bucket regions; packed src|ldst<<16 (nN<=65536) ---------
__global__ __launch_bounds__(256) void k_bin(const int* __restrict__ src,
                                             const int* __restrict__ dst,
                                             const int* __restrict__ bktBase,
                                             int* __restrict__ bktCursor,
                                             unsigned* __restrict__ binned,
                                             int nE, int nBkt) {
  __shared__ int hist[MAXBKT];
  __shared__ int boff[MAXBKT];
  int t = threadIdx.x;
  hist[t] = 0; hist[t + 256] = 0;
  __syncthreads();

  int eb = blockIdx.x * BIN_BATCH;
  unsigned pk[16];
  short bkt[16];
  int rk[16];
#pragma unroll
  for (int i = 0; i < 16; i++) {
    int e = eb + t + i * 256;
    if (e < nE) {
      int s = src[e], d = dst[e];
      bkt[i] = (short)(d >> BKT_SHIFT);
      pk[i] = (unsigned)s | ((unsigned)(d & (BKT_NODES - 1)) << 16);
      rk[i] = atomicAdd(&hist[d >> BKT_SHIFT], 1);
    } else rk[i] = -1;
  }
  __syncthreads();
  for (int i = t; i < nBkt; i += 256)
    boff[i] = hist[i] ? atomicAdd(&bktCursor[i], hist[i]) : 0;
  __syncthreads();
#pragma unroll
  for (int i = 0; i < 16; i++) {
    if (rk[i] >= 0) {
      int b = bkt[i];
      binned[bktBase[b] + boff[b] + rk[i]] = pk[i];
    }
  }
}

// ---- per-bucket CSR build + placement (all LDS atomics, localized writes) ---
__global__ __launch_bounds__(256) void k_build(const unsigned* __restrict__ binned,
                                               const int* __restrict__ bktBase,
                                               int* __restrict__ start,
                                               float* __restrict__ invdeg,
                                               int* __restrict__ srcSorted,
                                               int nN, int nE) {
  __shared__ int cnt[BKT_NODES];
  __shared__ int sc[BKT_NODES];
  __shared__ int cur[BKT_NODES];
  int b = blockIdx.x, t = threadIdx.x;
  int base = b << BKT_SHIFT;
  int e0 = bktBase[b], e1 = bktBase[b + 1];

  if (t < BKT_NODES) { cnt[t] = 0; cur[t] = 0; }
  __syncthreads();
  for (int i = e0 + t; i < e1; i += 256)
    atomicAdd(&cnt[binned[i] >> 16], 1);
  __syncthreads();
  if (t < BKT_NODES) sc[t] = cnt[t];
  __syncthreads();
  for (int off = 1; off < BKT_NODES; off <<= 1) {
    int u = (t < BKT_NODES && t >= off) ? sc[t - off] : 0;
    __syncthreads();
    if (t < BKT_NODES && t >= off) sc[t] += u;
    __syncthreads();
  }
  if (t < BKT_NODES) {
    int n = base + t;
    if (n < nN) {
      start[n] = e0 + sc[t] - cnt[t];
      invdeg[n] = 1.0f / fmaxf((float)cnt[t], 1.0f);
    }
  }
  if (b == 0 && t == 0) start[nN] = nE;
  __syncthreads();
  for (int i = e0 + t; i < e1; i += 256) {
    unsigned p = binned[i];
    int ld = p >> 16;
    int pos = e0 + sc[ld] - cnt[ld] + atomicAdd(&cur[ld], 1);
    srcSorted[pos] = (int)(p & 0xFFFFu);
  }
}

// ---- gather-mean over bf16 rows: 16 lanes/node, unroll x8 (R12-proven) ------
#define ACC8(v)                                          \
  a0 += __uint_as_float((v).x << 16);                    \
  a1 += __uint_as_float((v).x & 0xFFFF0000u);            \
  a2 += __uint_as_float((v).y << 16);                    \
  a3 += __uint_as_float((v).y & 0xFFFF0000u);            \
  a4 += __uint_as_float((v).z << 16);                    \
  a5 += __uint_as_float((v).z & 0xFFFF0000u);            \
  a6 += __uint_as_float((v).w << 16);                    \
  a7 += __uint_as_float((v).w & 0xFFFF0000u);

__global__ __launch_bounds__(256) void k_gather(const unsigned short* __restrict__ xbf,
                                                const int* __restrict__ srcSorted,
                                                const int* __restrict__ start,
                                                const float* __restrict__ invdeg,
                                                unsigned short* __restrict__ aggbf,
                                                int nN) {
  int gid = blockIdx.x * 256 + threadIdx.x;
  int node = gid >> 4;
  if (node >= nN) return;
  int c = (gid & 15) << 3;
  const unsigned short* xb = xbf + c;
  int s0 = start[node], s1 = start[node + 1];
  float a0 = 0.f, a1 = 0.f, a2 = 0.f, a3 = 0.f,
        a4 = 0.f, a5 = 0.f, a6 = 0.f, a7 = 0.f;
  int i = s0;
  for (; i + 8 <= s1; i += 8) {
    int s_0 = srcSorted[i],     s_1 = srcSorted[i + 1];
    int s_2 = srcSorted[i + 2], s_3 = srcSorted[i + 3];
    int s_4 = srcSorted[i + 4], s_5 = srcSorted[i + 5];
    int s_6 = srcSorted[i + 6], s_7 = srcSorted[i + 7];
    uint4 v0 = *reinterpret_cast<const uint4*>(xb + (size_t)s_0 * NCH);
    uint4 v1 = *reinterpret_cast<const uint4*>(xb + (size_t)s_1 * NCH);
    uint4 v2 = *reinterpret_cast<const uint4*>(xb + (size_t)s_2 * NCH);
    uint4 v3 = *reinterpret_cast<const uint4*>(xb + (size_t)s_3 * NCH);
    uint4 v4 = *reinterpret_cast<const uint4*>(xb + (size_t)s_4 * NCH);
    uint4 v5 = *reinterpret_cast<const uint4*>(xb + (size_t)s_5 * NCH);
    uint4 v6 = *reinterpret_cast<const uint4*>(xb + (size_t)s_6 * NCH);
    uint4 v7 = *reinterpret_cast<const uint4*>(xb + (size_t)s_7 * NCH);
    ACC8(v0) ACC8(v1) ACC8(v2) ACC8(v3)
    ACC8(v4) ACC8(v5) ACC8(v6) ACC8(v7)
  }
  for (; i + 4 <= s1; i += 4) {
    int s_0 = srcSorted[i],     s_1 = srcSorted[i + 1];
    int s_2 = srcSorted[i + 2], s_3 = srcSorted[i + 3];
    uint4 v0 = *reinterpret_cast<const uint4*>(xb + (size_t)s_0 * NCH);
    uint4 v1 = *reinterpret_cast<const uint4*>(xb + (size_t)s_1 * NCH);
    uint4 v2 = *reinterpret_cast<const uint4*>(xb + (size_t)s_2 * NCH);
    uint4 v3 = *reinterpret_cast<const uint4*>(xb + (size_t)s_3 * NCH);
    ACC8(v0) ACC8(v1) ACC8(v2) ACC8(v3)
  }
  for (; i < s1; i++) {
    int s = srcSorted[i];
    uint4 v = *reinterpret_cast<const uint4*>(xb + (size_t)s * NCH);
    ACC8(v)
  }
  float idg = invdeg[node];
  uint4 o;
  o.x = (unsigned)f2bf_rne(a0 * idg) | ((unsigned)f2bf_rne(a1 * idg) << 16);
  o.y = (unsigned)f2bf_rne(a2 * idg) | ((unsigned)f2bf_rne(a3 * idg) << 16);
  o.z = (unsigned)f2bf_rne(a4 * idg) | ((unsigned)f2bf_rne(a5 * idg) << 16);
  o.w = (unsigned)f2bf_rne(a6 * idg) | ((unsigned)f2bf_rne(a7 * idg) << 16);
  *reinterpret_cast<uint4*>(aggbf + (size_t)node * NCH + c) = o;
}

// ---- MFMA linear: out = [relu]( [agg|x]_bf16 @ Wf + b ) — R12-proven --------
__global__ __launch_bounds__(256, 4) void k_linear_mfma(
    const unsigned short* __restrict__ aggbf, const unsigned short* __restrict__ xinbf,
    const unsigned short* __restrict__ Wf,
    const float* __restrict__ bias, float* __restrict__ outF,
    unsigned short* __restrict__ outBf, int relu, int nNodes) {
  int t = threadIdx.x;
  int wave = t >> 6;
  int lane = t & 63;
  int l15 = lane & 15;
  int lq  = lane >> 4;
  int r0 = (blockIdx.x * 4 + wave) * 16;

  const bf16x8* WV = reinterpret_cast<const bf16x8*>(Wf) + lane;

  f32x4 acc[8];
#pragma unroll
  for (int i = 0; i < 8; i++) acc[i] = (f32x4){0.f, 0.f, 0.f, 0.f};

  int arow = r0 + l15;
  if (arow >= nNodes) arow = nNodes - 1;

#pragma unroll
  for (int kc = 0; kc < 8; kc++) {
    const unsigned short* ab = (kc < 4) ? aggbf : xinbf;
    int k128 = (kc & 3) * 32 + lq * 8;
    bf16x8 a = *reinterpret_cast<const bf16x8*>(ab + (size_t)arow * NCH + k128);
#pragma unroll
    for (int nt = 0; nt < 8; nt++) {
      bf16x8 bw = WV[(kc * 8 + nt) * 64];
      acc[nt] = __builtin_amdgcn_mfma_f32_16x16x32_bf16(a, bw, acc[nt], 0, 0, 0);
    }
  }

#pragma unroll
  for (int nt = 0; nt < 8; nt++) {
    int col = nt * 16 + l15;
    float bv = bias[col];
#pragma unroll
    for (int i = 0; i < 4; i++) {
      int row = r0 + lq * 4 + i;
      if (row < nNodes) {
        float v = acc[nt][i] + bv;
        if (relu) v = fmaxf(v, 0.f);
        if (outBf) outBf[(size_t)row * NCH + col] = f2bf_rne(v);
        else       outF[(size_t)row * NCH + col] = v;
      }
    }
  }
}

extern "C" void kernel_launch(void* const* d_in, const int* in_sizes, int n_in,
                              void* d_out, int out_size, void* d_ws, size_t ws_size,
                              hipStream_t stream) {
  const float* x   = (const float*)d_in[0];
  const int*   ei  = (const int*)d_in[1];
  const float* W1l = (const float*)d_in[2];
  const float* W1r = (const float*)d_in[3];
  const float* b1  = (const float*)d_in[4];
  const float* W2l = (const float*)d_in[5];
  const float* W2r = (const float*)d_in[6];
  const float* b2  = (const float*)d_in[7];
  float* out = (float*)d_out;

  const int nE = in_sizes[1] / 2;     // 800000
  const int nN = in_sizes[0] / NCH;   // 50000 (<= 65536 required by packing)
  const int* src = ei;
  const int* dst = ei + nE;
  const int nBkt = (nN + BKT_NODES - 1) >> BKT_SHIFT;   // 391

  size_t bfBytes = (size_t)nN * NCH * sizeof(unsigned short);   // 12.8 MB
  size_t wBytes  = (size_t)128 * 256 * sizeof(unsigned short);  // 64 KB
  auto align256 = [](size_t v) { return (v + 255) & ~(size_t)255; };

  char* ws = (char*)d_ws;
  unsigned short* xbf   = (unsigned short*)ws;  ws += bfBytes;
  unsigned short* aggbf = (unsigned short*)ws;  ws += bfBytes;
  unsigned short* hbf   = (unsigned short*)ws;  ws += bfBytes;
  unsigned* binned = (unsigned*)ws;             ws += align256((size_t)nE * sizeof(unsigned));
  int*   srcSorted = (int*)ws;                  ws += align256((size_t)nE * sizeof(int));
  int*   startRow  = (int*)ws;                  ws += align256((size_t)(nN + 1) * sizeof(int));
  float* invdeg    = (float*)ws;                ws += align256((size_t)nN * sizeof(float));
  int*   partial   = (int*)ws;                  ws += (size_t)NHIST * MAXBKT * sizeof(int);  // 1 MB
  int*   bktCursor = (int*)ws;                  ws += MAXBKT * sizeof(int);
  int*   bktBase   = (int*)ws;                  ws += align256((MAXBKT + 1) * sizeof(int));
  unsigned short* W1f = (unsigned short*)ws;    ws += wBytes;
  unsigned short* W2f = (unsigned short*)ws;    ws += wBytes;

  int n8 = nN * NCH / 8;                        // 800000, multiple of 256
  int prepBlocks = (n8 + 2 * 32768) / 256;      // 3381 exactly

  // ---- merged hist+prep, then scan / bin / build (no memset anywhere) ----
  k_prep_hist<<<NHIST + prepBlocks, 256, 0, stream>>>(dst, partial, x, xbf,
                                                      W1l, W1r, W2l, W2r,
                                                      W1f, W2f, nE, n8);
  k_bktscan<<<1, 512, 0, stream>>>(partial, bktBase, bktCursor, nBkt);
  k_bin<<<(nE + BIN_BATCH - 1) / BIN_BATCH, 256, 0, stream>>>(src, dst, bktBase,
                                                              bktCursor, binned, nE, nBkt);
  k_build<<<nBkt, 256, 0, stream>>>(binned, bktBase, startRow, invdeg, srcSorted, nN, nE);

  int gatherBlocks = (nN * 16 + 255) / 256;     // 16 lanes per node
  int linBlocks = (nN + 63) / 64;               // 16 rows/wave, 4 waves

  // ---- layer 1 ----
  k_gather<<<gatherBlocks, 256, 0, stream>>>(xbf, srcSorted, startRow, invdeg, aggbf, nN);
  k_linear_mfma<<<linBlocks, 256, 0, stream>>>(aggbf, xbf, W1f, b1,
                                               nullptr, hbf, 1, nN);

  // ---- layer 2 ----
  k_gather<<<gatherBlocks, 256, 0, stream>>>(hbf, srcSorted, startRow, invdeg, aggbf, nN);
  k_linear_mfma<<<linBlocks, 256, 0, stream>>>(aggbf, hbf, W2f, b2,
                                               out, nullptr, 0, nN);
}

// Round 14
// 147.655 us; speedup vs baseline: 1.1007x; 1.1007x over previous
//
#include <hip/hip_runtime.h>

#define NCH 128
#define MAXBKT 512          // supports nN <= 65536 at 128 nodes/bucket
#define BKT_SHIFT 7         // 128 nodes per bucket
#define BKT_NODES 128
#define BIN_BATCH 4096      // edges per k_bin block (16/thread) — R8-proven
#define NHIST 128           // histogram blocks (R12-proven optimum)

typedef __attribute__((ext_vector_type(8))) short bf16x8;
typedef __attribute__((ext_vector_type(4))) float f32x4;

__device__ __forceinline__ unsigned short f2bf_rne(float f) {
  unsigned u = __float_as_uint(f);
  unsigned r = u + 0x7FFF + ((u >> 16) & 1);
  return (unsigned short)(r >> 16);
}

// ---- bucket histogram: per-block partials, NO global atomics, NO init -------
__global__ __launch_bounds__(256) void k_bkthist(const int* __restrict__ dst,
                                                 int* __restrict__ partial,
                                                 int nE, int nBkt) {
  __shared__ int h[MAXBKT];
  int t = threadIdx.x;
  h[t] = 0; h[t + 256] = 0;
  __syncthreads();
  for (int e = blockIdx.x * 256 + t; e < nE; e += NHIST * 256)
    atomicAdd(&h[dst[e] >> BKT_SHIFT], 1);
  __syncthreads();
  partial[blockIdx.x * MAXBKT + t] = h[t];
  partial[blockIdx.x * MAXBKT + t + 256] = h[t + 256];
}

// ---- sum partials + scan -> bktBase; zero bktCursor (replaces memset) -------
__global__ __launch_bounds__(512) void k_bktscan(const int* __restrict__ partial,
                                                 int* __restrict__ bktBase,
                                                 int* __restrict__ bktCursor, int nBkt) {
  __shared__ int sc[512];
  int t = threadIdx.x;
  int v = 0;
#pragma unroll 8
  for (int b = 0; b < NHIST; b++) v += partial[b * MAXBKT + t];
  sc[t] = v;
  __syncthreads();
  for (int off = 1; off < 512; off <<= 1) {
    int u = (t >= off) ? sc[t - off] : 0;
    __syncthreads();
    sc[t] += u;
    __syncthreads();
  }
  bktBase[t] = sc[t] - v;            // buckets >= nBkt have v=0; harmless
  if (t == 511) bktBase[512] = sc[511];
  bktCursor[t] = 0;
}

// ---- bin edges into bucket regions; packed src|ldst<<16 (nN<=65536) ---------
__global__ __launch_bounds__(256) void k_bin(const int* __restrict__ src,
                                             const int* __restrict__ dst,
                                             const int* __restrict__ bktBase,
                                             int* __restrict__ bktCursor,
                                             unsigned* __restrict__ binned,
                                             int nE, int nBkt) {
  __shared__ int hist[MAXBKT];
  __shared__ int boff[MAXBKT];
  int t = threadIdx.x;
  hist[t] = 0; hist[t + 256] = 0;
  __syncthreads();

  int eb = blockIdx.x * BIN_BATCH;
  unsigned pk[16];
  short bkt[16];
  int rk[16];
#pragma unroll
  for (int i = 0; i < 16; i++) {
    int e = eb + t + i * 256;
    if (e < nE) {
      int s = src[e], d = dst[e];
      bkt[i] = (short)(d >> BKT_SHIFT);
      pk[i] = (unsigned)s | ((unsigned)(d & (BKT_NODES - 1)) << 16);
      rk[i] = atomicAdd(&hist[d >> BKT_SHIFT], 1);
    } else rk[i] = -1;
  }
  __syncthreads();
  for (int i = t; i < nBkt; i += 256)
    boff[i] = hist[i] ? atomicAdd(&bktCursor[i], hist[i]) : 0;
  __syncthreads();
#pragma unroll
  for (int i = 0; i < 16; i++) {
    if (rk[i] >= 0) {
      int b = bkt[i];
      binned[bktBase[b] + boff[b] + rk[i]] = pk[i];
    }
  }
}

// ---- per-bucket CSR build + placement (all LDS atomics, localized writes) ---
__global__ __launch_bounds__(256) void k_build(const unsigned* __restrict__ binned,
                                               const int* __restrict__ bktBase,
                                               int* __restrict__ start,
                                               float* __restrict__ invdeg,
                                               int* __restrict__ srcSorted,
                                               int nN, int nE) {
  __shared__ int cnt[BKT_NODES];
  __shared__ int sc[BKT_NODES];
  __shared__ int cur[BKT_NODES];
  int b = blockIdx.x, t = threadIdx.x;
  int base = b << BKT_SHIFT;
  int e0 = bktBase[b], e1 = bktBase[b + 1];

  if (t < BKT_NODES) { cnt[t] = 0; cur[t] = 0; }
  __syncthreads();
  for (int i = e0 + t; i < e1; i += 256)
    atomicAdd(&cnt[binned[i] >> 16], 1);
  __syncthreads();
  if (t < BKT_NODES) sc[t] = cnt[t];
  __syncthreads();
  for (int off = 1; off < BKT_NODES; off <<= 1) {
    int u = (t < BKT_NODES && t >= off) ? sc[t - off] : 0;
    __syncthreads();
    if (t < BKT_NODES && t >= off) sc[t] += u;
    __syncthreads();
  }
  if (t < BKT_NODES) {
    int n = base + t;
    if (n < nN) {
      start[n] = e0 + sc[t] - cnt[t];
      invdeg[n] = 1.0f / fmaxf((float)cnt[t], 1.0f);
    }
  }
  if (b == 0 && t == 0) start[nN] = nE;
  __syncthreads();
  for (int i = e0 + t; i < e1; i += 256) {
    unsigned p = binned[i];
    int ld = p >> 16;
    int pos = e0 + sc[ld] - cnt[ld] + atomicAdd(&cur[ld], 1);
    srcSorted[pos] = (int)(p & 0xFFFFu);
  }
}

// ---- prep: fragment-ordered SINGLE bf16 weights (RNE) -----------------------
// Wf index = ((kc*8 + nt)*64 + lane)*8 + e; j = nt*16+(lane&15),
// k = kc*32+(lane>>4)*8+e. Single-bf16 W proven R12 (absmax stayed at floor).
__device__ __forceinline__ void prepW_elem(const float* __restrict__ Wl,
                                           const float* __restrict__ Wr,
                                           unsigned short* __restrict__ WF, int i) {
  int kc   = i >> 12;
  int r    = i & 4095;
  int nt   = r >> 9;
  int r2   = r & 511;
  int lane = r2 >> 3;
  int e    = r2 & 7;
  int j = nt * 16 + (lane & 15);
  int k = kc * 32 + (lane >> 4) * 8 + e;
  float w = (k < 128) ? Wl[j * 128 + k] : Wr[j * 128 + (k - 128)];
  WF[i] = f2bf_rne(w);
}

__global__ __launch_bounds__(256) void k_prep(const float* __restrict__ x,
                                              unsigned short* __restrict__ xbf,
                                              const float* __restrict__ W1l,
                                              const float* __restrict__ W1r,
                                              const float* __restrict__ W2l,
                                              const float* __restrict__ W2r,
                                              unsigned short* __restrict__ W1f,
                                              unsigned short* __restrict__ W2f,
                                              int n8) {
  int i = blockIdx.x * 256 + threadIdx.x;
  if (i < n8) {                       // n8 = nN*NCH/8, multiple of 256
    const float4* p = reinterpret_cast<const float4*>(x + (size_t)i * 8);
    float4 v0 = p[0], v1 = p[1];
    uint4 o;
    o.x = (unsigned)f2bf_rne(v0.x) | ((unsigned)f2bf_rne(v0.y) << 16);
    o.y = (unsigned)f2bf_rne(v0.z) | ((unsigned)f2bf_rne(v0.w) << 16);
    o.z = (unsigned)f2bf_rne(v1.x) | ((unsigned)f2bf_rne(v1.y) << 16);
    o.w = (unsigned)f2bf_rne(v1.z) | ((unsigned)f2bf_rne(v1.w) << 16);
    *reinterpret_cast<uint4*>(xbf + (size_t)i * 8) = o;
  } else {
    int j = i - n8;
    if (j < 32768)       prepW_elem(W1l, W1r, W1f, j);
    else if (j < 65536)  prepW_elem(W2l, W2r, W2f, j - 32768);
  }
}

// ---- gather-mean over bf16 rows: 16 lanes/node, unroll x8 (R12-proven) ------
#define ACC8(v)                                          \
  a0 += __uint_as_float((v).x << 16);                    \
  a1 += __uint_as_float((v).x & 0xFFFF0000u);            \
  a2 += __uint_as_float((v).y << 16);                    \
  a3 += __uint_as_float((v).y & 0xFFFF0000u);            \
  a4 += __uint_as_float((v).z << 16);                    \
  a5 += __uint_as_float((v).z & 0xFFFF0000u);            \
  a6 += __uint_as_float((v).w << 16);                    \
  a7 += __uint_as_float((v).w & 0xFFFF0000u);

__global__ __launch_bounds__(256) void k_gather(const unsigned short* __restrict__ xbf,
                                                const int* __restrict__ srcSorted,
                                                const int* __restrict__ start,
                                                const float* __restrict__ invdeg,
                                                unsigned short* __restrict__ aggbf,
                                                int nN) {
  int gid = blockIdx.x * 256 + threadIdx.x;
  int node = gid >> 4;
  if (node >= nN) return;
  int c = (gid & 15) << 3;
  const unsigned short* xb = xbf + c;
  int s0 = start[node], s1 = start[node + 1];
  float a0 = 0.f, a1 = 0.f, a2 = 0.f, a3 = 0.f,
        a4 = 0.f, a5 = 0.f, a6 = 0.f, a7 = 0.f;
  int i = s0;
  for (; i + 8 <= s1; i += 8) {
    int s_0 = srcSorted[i],     s_1 = srcSorted[i + 1];
    int s_2 = srcSorted[i + 2], s_3 = srcSorted[i + 3];
    int s_4 = srcSorted[i + 4], s_5 = srcSorted[i + 5];
    int s_6 = srcSorted[i + 6], s_7 = srcSorted[i + 7];
    uint4 v0 = *reinterpret_cast<const uint4*>(xb + (size_t)s_0 * NCH);
    uint4 v1 = *reinterpret_cast<const uint4*>(xb + (size_t)s_1 * NCH);
    uint4 v2 = *reinterpret_cast<const uint4*>(xb + (size_t)s_2 * NCH);
    uint4 v3 = *reinterpret_cast<const uint4*>(xb + (size_t)s_3 * NCH);
    uint4 v4 = *reinterpret_cast<const uint4*>(xb + (size_t)s_4 * NCH);
    uint4 v5 = *reinterpret_cast<const uint4*>(xb + (size_t)s_5 * NCH);
    uint4 v6 = *reinterpret_cast<const uint4*>(xb + (size_t)s_6 * NCH);
    uint4 v7 = *reinterpret_cast<const uint4*>(xb + (size_t)s_7 * NCH);
    ACC8(v0) ACC8(v1) ACC8(v2) ACC8(v3)
    ACC8(v4) ACC8(v5) ACC8(v6) ACC8(v7)
  }
  for (; i + 4 <= s1; i += 4) {
    int s_0 = srcSorted[i],     s_1 = srcSorted[i + 1];
    int s_2 = srcSorted[i + 2], s_3 = srcSorted[i + 3];
    uint4 v0 = *reinterpret_cast<const uint4*>(xb + (size_t)s_0 * NCH);
    uint4 v1 = *reinterpret_cast<const uint4*>(xb + (size_t)s_1 * NCH);
    uint4 v2 = *reinterpret_cast<const uint4*>(xb + (size_t)s_2 * NCH);
    uint4 v3 = *reinterpret_cast<const uint4*>(xb + (size_t)s_3 * NCH);
    ACC8(v0) ACC8(v1) ACC8(v2) ACC8(v3)
  }
  for (; i < s1; i++) {
    int s = srcSorted[i];
    uint4 v = *reinterpret_cast<const uint4*>(xb + (size_t)s * NCH);
    ACC8(v)
  }
  float idg = invdeg[node];
  uint4 o;
  o.x = (unsigned)f2bf_rne(a0 * idg) | ((unsigned)f2bf_rne(a1 * idg) << 16);
  o.y = (unsigned)f2bf_rne(a2 * idg) | ((unsigned)f2bf_rne(a3 * idg) << 16);
  o.z = (unsigned)f2bf_rne(a4 * idg) | ((unsigned)f2bf_rne(a5 * idg) << 16);
  o.w = (unsigned)f2bf_rne(a6 * idg) | ((unsigned)f2bf_rne(a7 * idg) << 16);
  *reinterpret_cast<uint4*>(aggbf + (size_t)node * NCH + c) = o;
}

// ---- MFMA linear: out = [relu]( [agg|x]_bf16 @ Wf + b ) — R12-proven --------
__global__ __launch_bounds__(256, 4) void k_linear_mfma(
    const unsigned short* __restrict__ aggbf, const unsigned short* __restrict__ xinbf,
    const unsigned short* __restrict__ Wf,
    const float* __restrict__ bias, float* __restrict__ outF,
    unsigned short* __restrict__ outBf, int relu, int nNodes) {
  int t = threadIdx.x;
  int wave = t >> 6;
  int lane = t & 63;
  int l15 = lane & 15;
  int lq  = lane >> 4;
  int r0 = (blockIdx.x * 4 + wave) * 16;

  const bf16x8* WV = reinterpret_cast<const bf16x8*>(Wf) + lane;

  f32x4 acc[8];
#pragma unroll
  for (int i = 0; i < 8; i++) acc[i] = (f32x4){0.f, 0.f, 0.f, 0.f};

  int arow = r0 + l15;
  if (arow >= nNodes) arow = nNodes - 1;

#pragma unroll
  for (int kc = 0; kc < 8; kc++) {
    const unsigned short* ab = (kc < 4) ? aggbf : xinbf;
    int k128 = (kc & 3) * 32 + lq * 8;
    bf16x8 a = *reinterpret_cast<const bf16x8*>(ab + (size_t)arow * NCH + k128);
#pragma unroll
    for (int nt = 0; nt < 8; nt++) {
      bf16x8 bw = WV[(kc * 8 + nt) * 64];
      acc[nt] = __builtin_amdgcn_mfma_f32_16x16x32_bf16(a, bw, acc[nt], 0, 0, 0);
    }
  }

#pragma unroll
  for (int nt = 0; nt < 8; nt++) {
    int col = nt * 16 + l15;
    float bv = bias[col];
#pragma unroll
    for (int i = 0; i < 4; i++) {
      int row = r0 + lq * 4 + i;
      if (row < nNodes) {
        float v = acc[nt][i] + bv;
        if (relu) v = fmaxf(v, 0.f);
        if (outBf) outBf[(size_t)row * NCH + col] = f2bf_rne(v);
        else       outF[(size_t)row * NCH + col] = v;
      }
    }
  }
}

extern "C" void kernel_launch(void* const* d_in, const int* in_sizes, int n_in,
                              void* d_out, int out_size, void* d_ws, size_t ws_size,
                              hipStream_t stream) {
  const float* x   = (const float*)d_in[0];
  const int*   ei  = (const int*)d_in[1];
  const float* W1l = (const float*)d_in[2];
  const float* W1r = (const float*)d_in[3];
  const float* b1  = (const float*)d_in[4];
  const float* W2l = (const float*)d_in[5];
  const float* W2r = (const float*)d_in[6];
  const float* b2  = (const float*)d_in[7];
  float* out = (float*)d_out;

  const int nE = in_sizes[1] / 2;     // 800000
  const int nN = in_sizes[0] / NCH;   // 50000 (<= 65536 required by packing)
  const int* src = ei;
  const int* dst = ei + nE;
  const int nBkt = (nN + BKT_NODES - 1) >> BKT_SHIFT;   // 391

  size_t bfBytes = (size_t)nN * NCH * sizeof(unsigned short);   // 12.8 MB
  size_t wBytes  = (size_t)128 * 256 * sizeof(unsigned short);  // 64 KB
  auto align256 = [](size_t v) { return (v + 255) & ~(size_t)255; };

  char* ws = (char*)d_ws;
  unsigned short* xbf   = (unsigned short*)ws;  ws += bfBytes;
  unsigned short* aggbf = (unsigned short*)ws;  ws += bfBytes;
  unsigned short* hbf   = (unsigned short*)ws;  ws += bfBytes;
  unsigned* binned = (unsigned*)ws;             ws += align256((size_t)nE * sizeof(unsigned));
  int*   srcSorted = (int*)ws;                  ws += align256((size_t)nE * sizeof(int));
  int*   startRow  = (int*)ws;                  ws += align256((size_t)(nN + 1) * sizeof(int));
  float* invdeg    = (float*)ws;                ws += align256((size_t)nN * sizeof(float));
  int*   partial   = (int*)ws;                  ws += (size_t)NHIST * MAXBKT * sizeof(int);
  int*   bktCursor = (int*)ws;                  ws += MAXBKT * sizeof(int);
  int*   bktBase   = (int*)ws;                  ws += align256((MAXBKT + 1) * sizeof(int));
  unsigned short* W1f = (unsigned short*)ws;    ws += wBytes;
  unsigned short* W2f = (unsigned short*)ws;    ws += wBytes;

  // ---- CSR build (no memset anywhere) ----
  k_bkthist<<<NHIST, 256, 0, stream>>>(dst, partial, nE, nBkt);
  k_bktscan<<<1, 512, 0, stream>>>(partial, bktBase, bktCursor, nBkt);
  k_bin<<<(nE + BIN_BATCH - 1) / BIN_BATCH, 256, 0, stream>>>(src, dst, bktBase,
                                                              bktCursor, binned, nE, nBkt);
  k_build<<<nBkt, 256, 0, stream>>>(binned, bktBase, startRow, invdeg, srcSorted, nN, nE);

  // ---- fused feature/weight prep (one dispatch) ----
  {
    int n8 = nN * NCH / 8;                       // multiple of 256
    int total = n8 + 2 * 32768;
    k_prep<<<(total + 255) / 256, 256, 0, stream>>>(x, xbf, W1l, W1r, W2l, W2r,
                                                    W1f, W2f, n8);
  }

  int gatherBlocks = (nN * 16 + 255) / 256;     // 16 lanes per node (R8-proven)
  int linBlocks = (nN + 63) / 64;               // 16 rows/wave, 4 waves (R8-proven)

  // ---- layer 1 ----
  k_gather<<<gatherBlocks, 256, 0, stream>>>(xbf, srcSorted, startRow, invdeg, aggbf, nN);
  k_linear_mfma<<<linBlocks, 256, 0, stream>>>(aggbf, xbf, W1f, b1,
                                               nullptr, hbf, 1, nN);

  // ---- layer 2 ----
  k_gather<<<gatherBlocks, 256, 0, stream>>>(hbf, srcSorted, startRow, invdeg, aggbf, nN);
  k_linear_mfma<<<linBlocks, 256, 0, stream>>>(aggbf, hbf, W2f, b2,
                                               out, nullptr, 0, nN);
}